// Round 18
// baseline (212.108 us; speedup 1.0000x reference)
//
#include <hip/hip_runtime.h>
#include <stdint.h>

typedef _Float16 v8h __attribute__((ext_vector_type(8)));
typedef _Float16 v2h __attribute__((ext_vector_type(2)));
typedef float v4f __attribute__((ext_vector_type(4)));
typedef float v16f __attribute__((ext_vector_type(16)));

#define NPTS 2048
#define BATCH 16
#define KNN 20
#define PAIRS (NPTS * KNN)   // 40960 per batch

// ---------- helpers ----------
__device__ __forceinline__ unsigned pair_relu_h2(unsigned pu, unsigned qu) {
  v2h a = *(const v2h*)&pu;
  v2h b = *(const v2h*)&qu;
  v2h s = a + b;                                   // v_pk_add_f16
  v2h z = {(_Float16)0.f, (_Float16)0.f};
  v2h r = __builtin_elementwise_max(s, z);         // v_pk_max_f16 (relu)
  return *(const unsigned*)&r;
}
__device__ __forceinline__ float fmax3(float a, float b, float c) {
  return fmaxf(fmaxf(a, b), c);                    // fuses to v_max3_f32
}

// ---------- K1: fused exact-20NN + prep(M2, in LDS) + pq emission + H/done zero ----------
// R17 core (session best). R21 lesson: dependency DEPTH beats inst COUNT
// (binary-search tau with serial VALU->SALU chain lost to the ILP-rich
// bitonic). R23: also zeros the per-batch done[] counters for gemm's
// last-block fc election.
__global__ __launch_bounds__(512, 2) void knn_kernel(
    const float* __restrict__ x, int* __restrict__ idxOut,
    const float* __restrict__ W1, const float* __restrict__ W2,
    unsigned short* __restrict__ p, unsigned short* __restrict__ q,
    int* __restrict__ H, int* __restrict__ done) {
  __shared__ float4 pts[NPTS];                    // 32 KB (x,y,z,|.|^2)
  __shared__ unsigned long long cand[8][8][64];   // 32 KB, wave-private
  __shared__ float M2s[128][6];                   // 3 KB: [ch][a0..2 | b0..2]
  int b = blockIdx.x >> 5;
  int qblk = blockIdx.x & 31;
  const float* xb = x + b * 3 * NPTS;

  if (qblk == 0 && threadIdx.x < 256) H[b * 256 + threadIdx.x] = 0;
  if (qblk == 0 && threadIdx.x == 256) done[b] = 0;

  for (int i = threadIdx.x; i < NPTS; i += 512) {
    float X = xb[i], Y = xb[NPTS + i], Z = xb[2 * NPTS + i];
    pts[i] = make_float4(X, Y, Z, X * X + Y * Y + Z * Z);
  }

  // M2 once per block: thread o (<128) computes channel o's 6 coefficients.
  if (threadIdx.x < 128) {
    int o = threadIdx.x;
    const float* w2 = W2 + o * 64;
    float a0 = 0, a1 = 0, a2 = 0, a3 = 0, a4 = 0, a5 = 0;
    for (int i = 0; i < 64; ++i) {
      const float* w1r = W1 + i * 6;
      float w = w2[i];
      a0 += w * w1r[0]; a1 += w * w1r[1]; a2 += w * w1r[2];
      a3 += w * (w1r[3] - w1r[0]); a4 += w * (w1r[4] - w1r[1]); a5 += w * (w1r[5] - w1r[2]);
    }
    M2s[o][0] = a0; M2s[o][1] = a1; M2s[o][2] = a2;
    M2s[o][3] = a3; M2s[o][4] = a4; M2s[o][5] = a5;
  }
  __syncthreads();

  int wid = threadIdx.x >> 6, lane = threadIdx.x & 63;
  int qbase = qblk * 64 + wid * 8;                // 8 queries per wave

  // pq fold: emit p/q rows for this wave's 8 queries (coalesced stores).
  {
    int o0 = lane * 2;
    float a0 = M2s[o0][0], a1 = M2s[o0][1], a2 = M2s[o0][2];
    float a3 = M2s[o0][3], a4 = M2s[o0][4], a5 = M2s[o0][5];
    float c0 = M2s[o0 + 1][0], c1 = M2s[o0 + 1][1], c2 = M2s[o0 + 1][2];
    float c3 = M2s[o0 + 1][3], c4 = M2s[o0 + 1][4], c5 = M2s[o0 + 1][5];
    unsigned* pw = (unsigned*)p;
    unsigned* qw = (unsigned*)q;
#pragma unroll
    for (int g = 0; g < 8; ++g) {
      int j = qbase + g;
      float4 qp = pts[j];                         // broadcast LDS read
      float p0 = a0 * qp.x + a1 * qp.y + a2 * qp.z;
      float p1 = c0 * qp.x + c1 * qp.y + c2 * qp.z;
      float q0 = a3 * qp.x + a4 * qp.y + a5 * qp.z;
      float q1 = c3 * qp.x + c4 * qp.y + c5 * qp.z;
      size_t base = ((size_t)(b * NPTS + j)) * 64 + lane;
      auto hp = __builtin_amdgcn_cvt_pkrtz(p0, p1);
      auto hq = __builtin_amdgcn_cvt_pkrtz(q0, q1);
      pw[base] = *(const unsigned*)&hp;
      qw[base] = *(const unsigned*)&hq;
    }
  }

  float m2x[8], m2y[8], m2z[8], mn[8];
#pragma unroll
  for (int g = 0; g < 8; ++g) {
    float4 qp = pts[qbase + g];                   // broadcast read
    m2x[g] = -2.f * qp.x; m2y[g] = -2.f * qp.y; m2z[g] = -2.f * qp.z;
    mn[g] = 1e30f;
  }

  // pass 1: per-lane min over its 32 points, all 8 queries share the load
  for (int s = 0; s < 32; ++s) {
    float4 P = pts[s * 64 + lane];
#pragma unroll
    for (int g = 0; g < 8; ++g) {
      float d = fmaf(m2x[g], P.x, fmaf(m2y[g], P.y, fmaf(m2z[g], P.z, P.w)));
      mn[g] = fminf(mn[g], d);
    }
  }

  // tau[g] = 20th-smallest lane-min (upper bound on d'_(20)), inflated
  float tau[8];
#pragma unroll
  for (int g = 0; g < 8; ++g) {
    float v = mn[g];
    for (int k = 2; k <= 64; k <<= 1) {
      for (int j = k >> 1; j > 0; j >>= 1) {
        float o = __shfl_xor(v, j);
        bool low = (lane & j) == 0;
        bool up = (lane & k) == 0;
        v = (low == up) ? fminf(v, o) : fmaxf(v, o);
      }
    }
    float t = __shfl(v, 19);
    tau[g] = t + fabsf(t) * 4e-6f + 1e-6f;
  }

  // pass 2: recompute, ballot-compact candidates per query
  int cnt[8] = {0, 0, 0, 0, 0, 0, 0, 0};
  for (int s = 0; s < 32; ++s) {
    int i = s * 64 + lane;
    float4 P = pts[i];
#pragma unroll
    for (int g = 0; g < 8; ++g) {
      float d = fmaf(m2x[g], P.x, fmaf(m2y[g], P.y, fmaf(m2z[g], P.z, P.w)));
      bool take = d <= tau[g];
      unsigned long long mb = __ballot(take);
      if (take) {
        int pos = cnt[g] + __popcll(mb & ((1ull << lane) - 1ull));
        if (pos < 64) {
          unsigned kd = __float_as_uint(d + 64.f);   // d > -64: monotone key
          cand[wid][g][pos] = (((unsigned long long)kd) << 32) | (unsigned)i;
        }
      }
      cnt[g] += __popcll(mb);
    }
  }
  // cand written & read by the same wave: no __syncthreads needed.

  // rank-count select: broadcast reads; keys unique (index tiebreak).
#pragma unroll
  for (int g = 0; g < 8; ++g) {
    int nc = cnt[g] < 64 ? cnt[g] : 64;
    unsigned long long k0 = (lane < nc) ? cand[wid][g][lane] : ~0ull;
    int r0 = 0;
    for (int i = 0; i < nc; ++i) r0 += (cand[wid][g][i] < k0) ? 1 : 0;
    long long obase = ((long long)b * NPTS + qbase + g) * KNN;
    if (lane < nc && r0 < KNN) idxOut[obase + r0] = (int)(k0 & 0xffffffffu);
  }
}

// ---------- K2: h3 = relu(W3 · relu(p_j+q_n)) MFMA + max-reduce + fused FC ----------
// R14 structure (measured 50.5us, MfmaUtil 33% = its equilibrium).
// R23: fc fused via last-block election — after atomicMax H-writes:
// threadfence (device release) -> syncthreads -> t0 atomicAdd(done[b])
// (device scope); the 64th incrementer's wave 0 reads H via device-scope
// atomic loads (fence-ordered, no stale-L2 path) and computes the 10 FC
// outputs (~1us tail on 16/1024 blocks). Removes the fc dispatch (~2.5us
// gap + ~3us kernel per R16's measured per-dispatch cost).
// R11 lesson: launch_bounds (256,3), never (256,4) (VGPR cap -> spill).
__global__ __launch_bounds__(256, 3) void gemm_max_kernel(
    const unsigned short* __restrict__ p, const unsigned short* __restrict__ q,
    const int* __restrict__ idx, const float* __restrict__ W3, int* __restrict__ H,
    int* __restrict__ done, const float* __restrict__ fcw,
    const float* __restrict__ fcb, float* __restrict__ out) {
  __shared__ __align__(16) unsigned short h2s[2][2][32 * 128];  // 32 KB: dbuf x 2 tiles

  int b = blockIdx.x & 15;
  int w = blockIdx.x >> 4;            // 0..63
  int t = threadIdx.x;                // 0..255
  int lane = t & 63, wid = t >> 6;    // 4 waves
  int col = lane & 31, hi = lane >> 5;

  // B fragments: wave owns channels [wid*64, wid*64+64) as 2 ntiles.
  v8h bfr0[8], bfr1[8];
#pragma unroll
  for (int kk = 0; kk < 8; ++kk) {
    const float* s0 = W3 + (size_t)(wid * 64 + col) * 128 + kk * 16 + hi * 8;
    const float* s1 = s0 + 32 * 128;
    v8h f0, f1;
#pragma unroll
    for (int jj = 0; jj < 8; ++jj) { f0[jj] = (_Float16)s0[jj]; f1[jj] = (_Float16)s1[jj]; }
    bfr0[kk] = f0; bfr1[kk] = f1;
  }

  const unsigned short* pB = p + (size_t)b * NPTS * 128;
  const unsigned short* qB = q + (size_t)b * NPTS * 128;
  const int* idxB = idx + (size_t)b * PAIRS;

  int pm = t >> 3;        // pair-in-tile 0..31
  int c2 = t & 7;         // covers 16B units 2*c2, 2*c2+1 (32B of the row)
  int st0 = pm * 128 + (((c2 * 2) ^ (pm & 7)) * 8);
  int st1 = pm * 128 + (((c2 * 2 + 1) ^ (pm & 7)) * 8);

  const int NT = PAIRS / 32;          // 1280 tiles; iter = {T, T+64}, T += 128

  uint4 PA0, PA1, QA0, QA1, PB0, PB1, QB0, QB1;
  int jnA, jnB;
  {
    int prA = w * 32 + pm, prB = (w + 64) * 32 + pm;
    int jA = idxB[prA] & (NPTS - 1);
    int jB = idxB[prB] & (NPTS - 1);
    int nA = prA / 20, nB = prB / 20;
    PA0 = *(const uint4*)(pB + (size_t)jA * 128 + c2 * 16);
    PA1 = *(const uint4*)(pB + (size_t)jA * 128 + c2 * 16 + 8);
    QA0 = *(const uint4*)(qB + (size_t)nA * 128 + c2 * 16);
    QA1 = *(const uint4*)(qB + (size_t)nA * 128 + c2 * 16 + 8);
    PB0 = *(const uint4*)(pB + (size_t)jB * 128 + c2 * 16);
    PB1 = *(const uint4*)(pB + (size_t)jB * 128 + c2 * 16 + 8);
    QB0 = *(const uint4*)(qB + (size_t)nB * 128 + c2 * 16);
    QB1 = *(const uint4*)(qB + (size_t)nB * 128 + c2 * 16 + 8);
    jnA = idxB[(w + 128) * 32 + pm];
    jnB = idxB[(w + 192) * 32 + pm];
  }

  float vmx0 = 0.f, vmx1 = 0.f;
  int buf = 0;
  for (int T = w; T < NT; T += 128) {   // 10 exact iterations
    uint4 R;
    R.x = pair_relu_h2(PA0.x, QA0.x); R.y = pair_relu_h2(PA0.y, QA0.y);
    R.z = pair_relu_h2(PA0.z, QA0.z); R.w = pair_relu_h2(PA0.w, QA0.w);
    *(uint4*)&h2s[buf][0][st0] = R;
    R.x = pair_relu_h2(PA1.x, QA1.x); R.y = pair_relu_h2(PA1.y, QA1.y);
    R.z = pair_relu_h2(PA1.z, QA1.z); R.w = pair_relu_h2(PA1.w, QA1.w);
    *(uint4*)&h2s[buf][0][st1] = R;
    R.x = pair_relu_h2(PB0.x, QB0.x); R.y = pair_relu_h2(PB0.y, QB0.y);
    R.z = pair_relu_h2(PB0.z, QB0.z); R.w = pair_relu_h2(PB0.w, QB0.w);
    *(uint4*)&h2s[buf][1][st0] = R;
    R.x = pair_relu_h2(PB1.x, QB1.x); R.y = pair_relu_h2(PB1.y, QB1.y);
    R.z = pair_relu_h2(PB1.z, QB1.z); R.w = pair_relu_h2(PB1.w, QB1.w);
    *(uint4*)&h2s[buf][1][st1] = R;
    __syncthreads();

    int Tn = T + 128;
    if (Tn < NT) {
      int prA = Tn * 32 + pm, prB = (Tn + 64) * 32 + pm;
      int jA = jnA & (NPTS - 1), jB = jnB & (NPTS - 1);
      int nA = prA / 20, nB = prB / 20;
      PA0 = *(const uint4*)(pB + (size_t)jA * 128 + c2 * 16);
      PA1 = *(const uint4*)(pB + (size_t)jA * 128 + c2 * 16 + 8);
      QA0 = *(const uint4*)(qB + (size_t)nA * 128 + c2 * 16);
      QA1 = *(const uint4*)(qB + (size_t)nA * 128 + c2 * 16 + 8);
      PB0 = *(const uint4*)(pB + (size_t)jB * 128 + c2 * 16);
      PB1 = *(const uint4*)(pB + (size_t)jB * 128 + c2 * 16 + 8);
      QB0 = *(const uint4*)(qB + (size_t)nB * 128 + c2 * 16);
      QB1 = *(const uint4*)(qB + (size_t)nB * 128 + c2 * 16 + 8);
      int T2 = T + 256;
      if (T2 < NT) {
        jnA = idxB[T2 * 32 + pm];
        jnB = idxB[(T2 + 64) * 32 + pm];
      }
    }

    {
      v16f acc0 = {0.f}, acc1 = {0.f};
#pragma unroll
      for (int kk = 0; kk < 8; ++kk) {
        v8h a = *(const v8h*)&h2s[buf][0][col * 128 + (((kk * 2 + hi) ^ (col & 7)) * 8)];
        acc0 = __builtin_amdgcn_mfma_f32_32x32x16_f16(a, bfr0[kk], acc0, 0, 0, 0);
        acc1 = __builtin_amdgcn_mfma_f32_32x32x16_f16(a, bfr1[kk], acc1, 0, 0, 0);
      }
      float m0 = fmax3(acc0[0], acc0[1], acc0[2]);
      float m1 = fmax3(acc0[3], acc0[4], acc0[5]);
      float m2 = fmax3(acc0[6], acc0[7], acc0[8]);
      float m3 = fmax3(acc0[9], acc0[10], acc0[11]);
      float m4 = fmax3(acc0[12], acc0[13], acc0[14]);
      vmx0 = fmax3(fmax3(m0, m1, m2), fmax3(m3, m4, acc0[15]), vmx0);
      float n0 = fmax3(acc1[0], acc1[1], acc1[2]);
      float n1 = fmax3(acc1[3], acc1[4], acc1[5]);
      float n2 = fmax3(acc1[6], acc1[7], acc1[8]);
      float n3 = fmax3(acc1[9], acc1[10], acc1[11]);
      float n4 = fmax3(acc1[12], acc1[13], acc1[14]);
      vmx1 = fmax3(fmax3(n0, n1, n2), fmax3(n3, n4, acc1[15]), vmx1);
    }
    {
      v16f acc0 = {0.f}, acc1 = {0.f};
#pragma unroll
      for (int kk = 0; kk < 8; ++kk) {
        v8h a = *(const v8h*)&h2s[buf][1][col * 128 + (((kk * 2 + hi) ^ (col & 7)) * 8)];
        acc0 = __builtin_amdgcn_mfma_f32_32x32x16_f16(a, bfr0[kk], acc0, 0, 0, 0);
        acc1 = __builtin_amdgcn_mfma_f32_32x32x16_f16(a, bfr1[kk], acc1, 0, 0, 0);
      }
      float m0 = fmax3(acc0[0], acc0[1], acc0[2]);
      float m1 = fmax3(acc0[3], acc0[4], acc0[5]);
      float m2 = fmax3(acc0[6], acc0[7], acc0[8]);
      float m3 = fmax3(acc0[9], acc0[10], acc0[11]);
      float m4 = fmax3(acc0[12], acc0[13], acc0[14]);
      vmx0 = fmax3(fmax3(m0, m1, m2), fmax3(m3, m4, acc0[15]), vmx0);
      float n0 = fmax3(acc1[0], acc1[1], acc1[2]);
      float n1 = fmax3(acc1[3], acc1[4], acc1[5]);
      float n2 = fmax3(acc1[6], acc1[7], acc1[8]);
      float n3 = fmax3(acc1[9], acc1[10], acc1[11]);
      float n4 = fmax3(acc1[12], acc1[13], acc1[14]);
      vmx1 = fmax3(fmax3(n0, n1, n2), fmax3(n3, n4, acc1[15]), vmx1);
    }
    buf ^= 1;
  }

  float v0 = fmaxf(vmx0, __shfl_xor(vmx0, 32));
  float v1 = fmaxf(vmx1, __shfl_xor(vmx1, 32));
  if (hi == 0) {
    atomicMax(&H[b * 256 + wid * 64 + col], __float_as_int(v0));
    atomicMax(&H[b * 256 + wid * 64 + 32 + col], __float_as_int(v1));
  }

  // ---- fused FC: last block of batch b computes out[b] ----
  __threadfence();                    // device-scope release of our H writes
  __syncthreads();                    // all lanes' atomics + fences done
  __shared__ int elect;
  if (t == 0) elect = atomicAdd(&done[b], 1);   // device-scope by default
  __syncthreads();
  if (elect == 63 && wid == 0) {      // 64th incrementer: all H final
    float hv[4];
#pragma unroll
    for (int k = 0; k < 4; ++k) {
      int hbits = __hip_atomic_load(&H[b * 256 + lane + 64 * k],
                                    __ATOMIC_RELAXED, __HIP_MEMORY_SCOPE_AGENT);
      hv[k] = __int_as_float(hbits);
    }
    for (int r = 0; r < 10; ++r) {
      float s = 0.f;
#pragma unroll
      for (int k = 0; k < 4; ++k) s += hv[k] * fcw[r * 256 + lane + 64 * k];
#pragma unroll
      for (int m = 32; m > 0; m >>= 1) s += __shfl_xor(s, m);
      if (lane == 0) out[b * 10 + r] = s + fcb[r];
    }
  }
}

// ---------- launch ----------
extern "C" void kernel_launch(void* const* d_in, const int* in_sizes, int n_in,
                              void* d_out, int out_size, void* d_ws, size_t ws_size,
                              hipStream_t stream) {
  const float* x   = (const float*)d_in[0];
  const float* W1  = (const float*)d_in[1];
  const float* W2  = (const float*)d_in[2];
  const float* W3  = (const float*)d_in[3];
  const float* fcw = (const float*)d_in[4];
  const float* fcb = (const float*)d_in[5];
  float* out = (float*)d_out;
  char* ws = (char*)d_ws;

  // workspace layout (needs ~20 MB)
  int* H     = (int*)(ws + 4096);           // 16 KB (16x256 f32-as-int)
  int* done  = (int*)(ws + 20480);          // 64 B (16 ints)
  int* idx   = (int*)(ws + 24576);          // 2.62 MB
  unsigned short* p = (unsigned short*)(ws + 3145728);   // 8.39 MB fp16
  unsigned short* q = (unsigned short*)(ws + 12582912);  // 8.39 MB fp16

  knn_kernel<<<BATCH * 32, 512, 0, stream>>>(x, idx, W1, W2, p, q, H, done);
  gemm_max_kernel<<<BATCH * 64, 256, 0, stream>>>(p, q, idx, W3, H, done, fcw, fcb, out);
}

// Round 19
// 155.364 us; speedup vs baseline: 1.3652x; 1.3652x over previous
//
#include <hip/hip_runtime.h>
#include <stdint.h>

typedef _Float16 v8h __attribute__((ext_vector_type(8)));
typedef _Float16 v2h __attribute__((ext_vector_type(2)));
typedef float v4f __attribute__((ext_vector_type(4)));
typedef float v16f __attribute__((ext_vector_type(16)));

#define NPTS 2048
#define BATCH 16
#define KNN 20
#define PAIRS (NPTS * KNN)   // 40960 per batch

// ---------- helpers ----------
__device__ __forceinline__ unsigned pair_relu_h2(unsigned pu, unsigned qu) {
  v2h a = *(const v2h*)&pu;
  v2h b = *(const v2h*)&qu;
  v2h s = a + b;                                   // v_pk_add_f16
  v2h z = {(_Float16)0.f, (_Float16)0.f};
  v2h r = __builtin_elementwise_max(s, z);         // v_pk_max_f16 (relu)
  return *(const unsigned*)&r;
}
__device__ __forceinline__ float fmax3(float a, float b, float c) {
  return fmaxf(fmaxf(a, b), c);                    // fuses to v_max3_f32
}

// ---------- K1: fused exact-20NN + prep(M2, in LDS) + pq emission + H zero ----------
// FINAL (R24 = R22 = R17 core, measured 158.0us total, session best).
// Lessons encoded: R16 per-thread prep fold (+18us) -> M2 once/block in LDS;
// R21 binary-search tau (serial VALU->SALU chain) lost to ILP-rich bitonic
// (dependency DEPTH beats inst COUNT); R23 per-block __threadfence for fc
// fusion poisoned the pipeline (+60us on gemm).
__global__ __launch_bounds__(512, 2) void knn_kernel(
    const float* __restrict__ x, int* __restrict__ idxOut,
    const float* __restrict__ W1, const float* __restrict__ W2,
    unsigned short* __restrict__ p, unsigned short* __restrict__ q,
    int* __restrict__ H) {
  __shared__ float4 pts[NPTS];                    // 32 KB (x,y,z,|.|^2)
  __shared__ unsigned long long cand[8][8][64];   // 32 KB, wave-private
  __shared__ float M2s[128][6];                   // 3 KB: [ch][a0..2 | b0..2]
  int b = blockIdx.x >> 5;
  int qblk = blockIdx.x & 31;
  const float* xb = x + b * 3 * NPTS;

  if (qblk == 0 && threadIdx.x < 256) H[b * 256 + threadIdx.x] = 0;

  for (int i = threadIdx.x; i < NPTS; i += 512) {
    float X = xb[i], Y = xb[NPTS + i], Z = xb[2 * NPTS + i];
    pts[i] = make_float4(X, Y, Z, X * X + Y * Y + Z * Z);
  }

  // M2 once per block: thread o (<128) computes channel o's 6 coefficients.
  if (threadIdx.x < 128) {
    int o = threadIdx.x;
    const float* w2 = W2 + o * 64;
    float a0 = 0, a1 = 0, a2 = 0, a3 = 0, a4 = 0, a5 = 0;
    for (int i = 0; i < 64; ++i) {
      const float* w1r = W1 + i * 6;
      float w = w2[i];
      a0 += w * w1r[0]; a1 += w * w1r[1]; a2 += w * w1r[2];
      a3 += w * (w1r[3] - w1r[0]); a4 += w * (w1r[4] - w1r[1]); a5 += w * (w1r[5] - w1r[2]);
    }
    M2s[o][0] = a0; M2s[o][1] = a1; M2s[o][2] = a2;
    M2s[o][3] = a3; M2s[o][4] = a4; M2s[o][5] = a5;
  }
  __syncthreads();

  int wid = threadIdx.x >> 6, lane = threadIdx.x & 63;
  int qbase = qblk * 64 + wid * 8;                // 8 queries per wave

  // pq fold: emit p/q rows for this wave's 8 queries (coalesced stores).
  {
    int o0 = lane * 2;
    float a0 = M2s[o0][0], a1 = M2s[o0][1], a2 = M2s[o0][2];
    float a3 = M2s[o0][3], a4 = M2s[o0][4], a5 = M2s[o0][5];
    float c0 = M2s[o0 + 1][0], c1 = M2s[o0 + 1][1], c2 = M2s[o0 + 1][2];
    float c3 = M2s[o0 + 1][3], c4 = M2s[o0 + 1][4], c5 = M2s[o0 + 1][5];
    unsigned* pw = (unsigned*)p;
    unsigned* qw = (unsigned*)q;
#pragma unroll
    for (int g = 0; g < 8; ++g) {
      int j = qbase + g;
      float4 qp = pts[j];                         // broadcast LDS read
      float p0 = a0 * qp.x + a1 * qp.y + a2 * qp.z;
      float p1 = c0 * qp.x + c1 * qp.y + c2 * qp.z;
      float q0 = a3 * qp.x + a4 * qp.y + a5 * qp.z;
      float q1 = c3 * qp.x + c4 * qp.y + c5 * qp.z;
      size_t base = ((size_t)(b * NPTS + j)) * 64 + lane;
      auto hp = __builtin_amdgcn_cvt_pkrtz(p0, p1);
      auto hq = __builtin_amdgcn_cvt_pkrtz(q0, q1);
      pw[base] = *(const unsigned*)&hp;
      qw[base] = *(const unsigned*)&hq;
    }
  }

  float m2x[8], m2y[8], m2z[8], mn[8];
#pragma unroll
  for (int g = 0; g < 8; ++g) {
    float4 qp = pts[qbase + g];                   // broadcast read
    m2x[g] = -2.f * qp.x; m2y[g] = -2.f * qp.y; m2z[g] = -2.f * qp.z;
    mn[g] = 1e30f;
  }

  // pass 1: per-lane min over its 32 points, all 8 queries share the load
  for (int s = 0; s < 32; ++s) {
    float4 P = pts[s * 64 + lane];
#pragma unroll
    for (int g = 0; g < 8; ++g) {
      float d = fmaf(m2x[g], P.x, fmaf(m2y[g], P.y, fmaf(m2z[g], P.z, P.w)));
      mn[g] = fminf(mn[g], d);
    }
  }

  // tau[g] = 20th-smallest lane-min (upper bound on d'_(20)), inflated
  float tau[8];
#pragma unroll
  for (int g = 0; g < 8; ++g) {
    float v = mn[g];
    for (int k = 2; k <= 64; k <<= 1) {
      for (int j = k >> 1; j > 0; j >>= 1) {
        float o = __shfl_xor(v, j);
        bool low = (lane & j) == 0;
        bool up = (lane & k) == 0;
        v = (low == up) ? fminf(v, o) : fmaxf(v, o);
      }
    }
    float t = __shfl(v, 19);
    tau[g] = t + fabsf(t) * 4e-6f + 1e-6f;
  }

  // pass 2: recompute, ballot-compact candidates per query
  int cnt[8] = {0, 0, 0, 0, 0, 0, 0, 0};
  for (int s = 0; s < 32; ++s) {
    int i = s * 64 + lane;
    float4 P = pts[i];
#pragma unroll
    for (int g = 0; g < 8; ++g) {
      float d = fmaf(m2x[g], P.x, fmaf(m2y[g], P.y, fmaf(m2z[g], P.z, P.w)));
      bool take = d <= tau[g];
      unsigned long long mb = __ballot(take);
      if (take) {
        int pos = cnt[g] + __popcll(mb & ((1ull << lane) - 1ull));
        if (pos < 64) {
          unsigned kd = __float_as_uint(d + 64.f);   // d > -64: monotone key
          cand[wid][g][pos] = (((unsigned long long)kd) << 32) | (unsigned)i;
        }
      }
      cnt[g] += __popcll(mb);
    }
  }
  // cand written & read by the same wave: no __syncthreads needed.

  // rank-count select: broadcast reads; keys unique (index tiebreak).
#pragma unroll
  for (int g = 0; g < 8; ++g) {
    int nc = cnt[g] < 64 ? cnt[g] : 64;
    unsigned long long k0 = (lane < nc) ? cand[wid][g][lane] : ~0ull;
    int r0 = 0;
    for (int i = 0; i < nc; ++i) r0 += (cand[wid][g][i] < k0) ? 1 : 0;
    long long obase = ((long long)b * NPTS + qbase + g) * KNN;
    if (lane < nc && r0 < KNN) idxOut[obase + r0] = (int)(k0 & 0xffffffffu);
  }
}

// ---------- K2: h3 = relu(W3 · relu(p_j+q_n)) via MFMA, fused max-reduce ----------
// R14 structure (measured 50.5us, MfmaUtil 33% = its equilibrium):
// TWO tiles per barrier, 4-buffer LDS (2 dbuf x 2 tiles = 32KB), 10 exact
// iters, batch->XCD pin, idx prefetch 2 iters ahead, swizzled LDS.
// Refuted alternatives: barrier-free gather (R15, coalescing 2.3x loss),
// producer-consumer waves (R20, 27% MfmaUtil clean), per-block threadfence
// fc fusion (R23, +60us pipeline poison).
// R11 lesson: launch_bounds (256,3), never (256,4) (VGPR cap -> spill).
__global__ __launch_bounds__(256, 3) void gemm_max_kernel(
    const unsigned short* __restrict__ p, const unsigned short* __restrict__ q,
    const int* __restrict__ idx, const float* __restrict__ W3, int* __restrict__ H) {
  __shared__ __align__(16) unsigned short h2s[2][2][32 * 128];  // 32 KB: dbuf x 2 tiles

  int b = blockIdx.x & 15;
  int w = blockIdx.x >> 4;            // 0..63
  int t = threadIdx.x;                // 0..255
  int lane = t & 63, wid = t >> 6;    // 4 waves
  int col = lane & 31, hi = lane >> 5;

  // B fragments: wave owns channels [wid*64, wid*64+64) as 2 ntiles.
  v8h bfr0[8], bfr1[8];
#pragma unroll
  for (int kk = 0; kk < 8; ++kk) {
    const float* s0 = W3 + (size_t)(wid * 64 + col) * 128 + kk * 16 + hi * 8;
    const float* s1 = s0 + 32 * 128;
    v8h f0, f1;
#pragma unroll
    for (int jj = 0; jj < 8; ++jj) { f0[jj] = (_Float16)s0[jj]; f1[jj] = (_Float16)s1[jj]; }
    bfr0[kk] = f0; bfr1[kk] = f1;
  }

  const unsigned short* pB = p + (size_t)b * NPTS * 128;
  const unsigned short* qB = q + (size_t)b * NPTS * 128;
  const int* idxB = idx + (size_t)b * PAIRS;

  int pm = t >> 3;        // pair-in-tile 0..31
  int c2 = t & 7;         // covers 16B units 2*c2, 2*c2+1 (32B of the row)
  int st0 = pm * 128 + (((c2 * 2) ^ (pm & 7)) * 8);
  int st1 = pm * 128 + (((c2 * 2 + 1) ^ (pm & 7)) * 8);

  const int NT = PAIRS / 32;          // 1280 tiles; iter = {T, T+64}, T += 128

  uint4 PA0, PA1, QA0, QA1, PB0, PB1, QB0, QB1;
  int jnA, jnB;
  {
    int prA = w * 32 + pm, prB = (w + 64) * 32 + pm;
    int jA = idxB[prA] & (NPTS - 1);
    int jB = idxB[prB] & (NPTS - 1);
    int nA = prA / 20, nB = prB / 20;
    PA0 = *(const uint4*)(pB + (size_t)jA * 128 + c2 * 16);
    PA1 = *(const uint4*)(pB + (size_t)jA * 128 + c2 * 16 + 8);
    QA0 = *(const uint4*)(qB + (size_t)nA * 128 + c2 * 16);
    QA1 = *(const uint4*)(qB + (size_t)nA * 128 + c2 * 16 + 8);
    PB0 = *(const uint4*)(pB + (size_t)jB * 128 + c2 * 16);
    PB1 = *(const uint4*)(pB + (size_t)jB * 128 + c2 * 16 + 8);
    QB0 = *(const uint4*)(qB + (size_t)nB * 128 + c2 * 16);
    QB1 = *(const uint4*)(qB + (size_t)nB * 128 + c2 * 16 + 8);
    jnA = idxB[(w + 128) * 32 + pm];
    jnB = idxB[(w + 192) * 32 + pm];
  }

  float vmx0 = 0.f, vmx1 = 0.f;
  int buf = 0;
  for (int T = w; T < NT; T += 128) {   // 10 exact iterations
    uint4 R;
    R.x = pair_relu_h2(PA0.x, QA0.x); R.y = pair_relu_h2(PA0.y, QA0.y);
    R.z = pair_relu_h2(PA0.z, QA0.z); R.w = pair_relu_h2(PA0.w, QA0.w);
    *(uint4*)&h2s[buf][0][st0] = R;
    R.x = pair_relu_h2(PA1.x, QA1.x); R.y = pair_relu_h2(PA1.y, QA1.y);
    R.z = pair_relu_h2(PA1.z, QA1.z); R.w = pair_relu_h2(PA1.w, QA1.w);
    *(uint4*)&h2s[buf][0][st1] = R;
    R.x = pair_relu_h2(PB0.x, QB0.x); R.y = pair_relu_h2(PB0.y, QB0.y);
    R.z = pair_relu_h2(PB0.z, QB0.z); R.w = pair_relu_h2(PB0.w, QB0.w);
    *(uint4*)&h2s[buf][1][st0] = R;
    R.x = pair_relu_h2(PB1.x, QB1.x); R.y = pair_relu_h2(PB1.y, QB1.y);
    R.z = pair_relu_h2(PB1.z, QB1.z); R.w = pair_relu_h2(PB1.w, QB1.w);
    *(uint4*)&h2s[buf][1][st1] = R;
    __syncthreads();

    int Tn = T + 128;
    if (Tn < NT) {
      int prA = Tn * 32 + pm, prB = (Tn + 64) * 32 + pm;
      int jA = jnA & (NPTS - 1), jB = jnB & (NPTS - 1);
      int nA = prA / 20, nB = prB / 20;
      PA0 = *(const uint4*)(pB + (size_t)jA * 128 + c2 * 16);
      PA1 = *(const uint4*)(pB + (size_t)jA * 128 + c2 * 16 + 8);
      QA0 = *(const uint4*)(qB + (size_t)nA * 128 + c2 * 16);
      QA1 = *(const uint4*)(qB + (size_t)nA * 128 + c2 * 16 + 8);
      PB0 = *(const uint4*)(pB + (size_t)jB * 128 + c2 * 16);
      PB1 = *(const uint4*)(pB + (size_t)jB * 128 + c2 * 16 + 8);
      QB0 = *(const uint4*)(qB + (size_t)nB * 128 + c2 * 16);
      QB1 = *(const uint4*)(qB + (size_t)nB * 128 + c2 * 16 + 8);
      int T2 = T + 256;
      if (T2 < NT) {
        jnA = idxB[T2 * 32 + pm];
        jnB = idxB[(T2 + 64) * 32 + pm];
      }
    }

    {
      v16f acc0 = {0.f}, acc1 = {0.f};
#pragma unroll
      for (int kk = 0; kk < 8; ++kk) {
        v8h a = *(const v8h*)&h2s[buf][0][col * 128 + (((kk * 2 + hi) ^ (col & 7)) * 8)];
        acc0 = __builtin_amdgcn_mfma_f32_32x32x16_f16(a, bfr0[kk], acc0, 0, 0, 0);
        acc1 = __builtin_amdgcn_mfma_f32_32x32x16_f16(a, bfr1[kk], acc1, 0, 0, 0);
      }
      float m0 = fmax3(acc0[0], acc0[1], acc0[2]);
      float m1 = fmax3(acc0[3], acc0[4], acc0[5]);
      float m2 = fmax3(acc0[6], acc0[7], acc0[8]);
      float m3 = fmax3(acc0[9], acc0[10], acc0[11]);
      float m4 = fmax3(acc0[12], acc0[13], acc0[14]);
      vmx0 = fmax3(fmax3(m0, m1, m2), fmax3(m3, m4, acc0[15]), vmx0);
      float n0 = fmax3(acc1[0], acc1[1], acc1[2]);
      float n1 = fmax3(acc1[3], acc1[4], acc1[5]);
      float n2 = fmax3(acc1[6], acc1[7], acc1[8]);
      float n3 = fmax3(acc1[9], acc1[10], acc1[11]);
      float n4 = fmax3(acc1[12], acc1[13], acc1[14]);
      vmx1 = fmax3(fmax3(n0, n1, n2), fmax3(n3, n4, acc1[15]), vmx1);
    }
    {
      v16f acc0 = {0.f}, acc1 = {0.f};
#pragma unroll
      for (int kk = 0; kk < 8; ++kk) {
        v8h a = *(const v8h*)&h2s[buf][1][col * 128 + (((kk * 2 + hi) ^ (col & 7)) * 8)];
        acc0 = __builtin_amdgcn_mfma_f32_32x32x16_f16(a, bfr0[kk], acc0, 0, 0, 0);
        acc1 = __builtin_amdgcn_mfma_f32_32x32x16_f16(a, bfr1[kk], acc1, 0, 0, 0);
      }
      float m0 = fmax3(acc0[0], acc0[1], acc0[2]);
      float m1 = fmax3(acc0[3], acc0[4], acc0[5]);
      float m2 = fmax3(acc0[6], acc0[7], acc0[8]);
      float m3 = fmax3(acc0[9], acc0[10], acc0[11]);
      float m4 = fmax3(acc0[12], acc0[13], acc0[14]);
      vmx0 = fmax3(fmax3(m0, m1, m2), fmax3(m3, m4, acc0[15]), vmx0);
      float n0 = fmax3(acc1[0], acc1[1], acc1[2]);
      float n1 = fmax3(acc1[3], acc1[4], acc1[5]);
      float n2 = fmax3(acc1[6], acc1[7], acc1[8]);
      float n3 = fmax3(acc1[9], acc1[10], acc1[11]);
      float n4 = fmax3(acc1[12], acc1[13], acc1[14]);
      vmx1 = fmax3(fmax3(n0, n1, n2), fmax3(n3, n4, acc1[15]), vmx1);
    }
    buf ^= 1;
  }

  float v0 = fmaxf(vmx0, __shfl_xor(vmx0, 32));
  float v1 = fmaxf(vmx1, __shfl_xor(vmx1, 32));
  if (hi == 0) {
    atomicMax(&H[b * 256 + wid * 64 + col], __float_as_int(v0));
    atomicMax(&H[b * 256 + wid * 64 + 32 + col], __float_as_int(v1));
  }
}

// ---------- K3: out = H @ fc_w^T + fc_b (one wave per output element) ----------
__global__ __launch_bounds__(64) void fc_kernel(const int* __restrict__ Hi,
                                                const float* __restrict__ fcw,
                                                const float* __restrict__ fcb,
                                                float* __restrict__ out) {
  int b = blockIdx.x / 10, r = blockIdx.x % 10;
  int lane = threadIdx.x;
  const float* Hb = (const float*)Hi + b * 256;
  float s = 0.f;
#pragma unroll
  for (int c = lane; c < 256; c += 64) s += Hb[c] * fcw[r * 256 + c];
#pragma unroll
  for (int m = 32; m > 0; m >>= 1) s += __shfl_xor(s, m);
  if (lane == 0) out[b * 10 + r] = s + fcb[r];
}

// ---------- launch ----------
extern "C" void kernel_launch(void* const* d_in, const int* in_sizes, int n_in,
                              void* d_out, int out_size, void* d_ws, size_t ws_size,
                              hipStream_t stream) {
  const float* x   = (const float*)d_in[0];
  const float* W1  = (const float*)d_in[1];
  const float* W2  = (const float*)d_in[2];
  const float* W3  = (const float*)d_in[3];
  const float* fcw = (const float*)d_in[4];
  const float* fcb = (const float*)d_in[5];
  float* out = (float*)d_out;
  char* ws = (char*)d_ws;

  // workspace layout (needs ~20 MB)
  int* H     = (int*)(ws + 4096);           // 16 KB (16x256 f32-as-int)
  int* idx   = (int*)(ws + 24576);          // 2.62 MB
  unsigned short* p = (unsigned short*)(ws + 3145728);   // 8.39 MB fp16
  unsigned short* q = (unsigned short*)(ws + 12582912);  // 8.39 MB fp16

  knn_kernel<<<BATCH * 32, 512, 0, stream>>>(x, idx, W1, W2, p, q, H);
  gemm_max_kernel<<<BATCH * 64, 256, 0, stream>>>(p, q, idx, W3, H);
  fc_kernel<<<BATCH * 10, 64, 0, stream>>>(H, fcw, fcb, out);
}